// Round 2
// baseline (4065.902 us; speedup 1.0000x reference)
//
#include <hip/hip_runtime.h>
#include <hip/hip_bf16.h>
#include <math.h>

#define NN   100000   // nodes
#define DD   202      // feature dim
#define ET   6        // edge types
#define MM   200000   // edges per type
#define NPOS 512
#define DE   1212     // DD*ET
#define KK   202      // GEMM K
#define KP   224      // K padded to 7*32
#define NP   1280     // N padded to 10*128
#define LDK  40       // LDS k-stride (32 + 8 pad), keeps 16B alignment, balanced banks

typedef __attribute__((ext_vector_type(8))) short bf16x8;
typedef __attribute__((ext_vector_type(4))) float f32x4;

static __device__ inline short f2b(float f) {
    __hip_bfloat16 h = __float2bfloat16(f);
    union { __hip_bfloat16 h; short s; } u; u.h = h; return u.s;
}

// ---------------- pos_gating: (512 x 202) = 2*sigmoid(pos_embs @ W_pos + b_pos)
__global__ void gating_kernel(const float* __restrict__ W_pos,
                              const float* __restrict__ b_pos,
                              float* __restrict__ gating) {
    int p = blockIdx.x;
    __shared__ float emb[DD];
    int t = threadIdx.x;
    if (t < 100) {
        float invf = expf(-((float)t / 100.0f) * 9.210340371976184f); // ln(10000)
        float si = (float)p * invf;
        emb[t]       = sinf(si);
        emb[100 + t] = cosf(si);
    } else if (t < 102) {
        emb[100 + t] = 0.0f;
    }
    __syncthreads();
    if (t < DD) {
        float acc = b_pos[t];
        for (int k = 0; k < DD; ++k) acc += emb[k] * W_pos[k * DD + t];
        gating[p * DD + t] = 2.0f / (1.0f + expf(-acc));
    }
}

// ---------------- W_transform (202x1212 fp32) -> Bt (1280x224 bf16, transposed, zero-padded)
__global__ void convB_kernel(const float* __restrict__ W, __hip_bfloat16* __restrict__ Bt) {
    int id = blockIdx.x * 256 + threadIdx.x;
    if (id >= NP * KP) return;
    int n = id / KP, k = id % KP;
    float v = (k < KK && n < DE) ? W[(size_t)k * DE + n] : 0.0f;
    Bt[id] = __float2bfloat16(v);
}

// ---------------- prop = A(100000x202 fp32) @ W(202x1212) + b  -> bf16, via MFMA
// 128x128 tile, BK=32, 4 waves each computing 64x64 (4x4 MFMA tiles of 16x16x32)
__global__ __launch_bounds__(256) void gemm_mfma(const float* __restrict__ A,
                                                 const __hip_bfloat16* __restrict__ Bt,
                                                 const float* __restrict__ bias,
                                                 __hip_bfloat16* __restrict__ C) {
    __shared__ short As[128 * LDK];
    __shared__ short Bs[128 * LDK];
    int t    = threadIdx.x;
    int lane = t & 63;
    int wave = t >> 6;
    int wm   = (wave >> 1) * 64;
    int wn   = (wave & 1) * 64;
    int q    = lane >> 4;
    int r16  = lane & 15;
    int row0 = blockIdx.y * 128;
    int col0 = blockIdx.x * 128;

    f32x4 acc[4][4] = {};

    for (int kc = 0; kc < KP; kc += 32) {
        // stage A: 128 rows x 32 k, fp32 -> bf16, zero-pad OOB
        #pragma unroll
        for (int i = 0; i < 2; ++i) {
            int c   = i * 256 + t;          // chunk 0..511
            int rr  = c >> 2;               // row in tile
            int kch = (c & 3) * 8;          // k offset in tile
            int grow = row0 + rr;
            short v[8];
            #pragma unroll
            for (int j = 0; j < 4; ++j) {
                int kp = kc + kch + 2 * j;  // even; pair valid iff kp < 202
                float2 f2 = make_float2(0.0f, 0.0f);
                if (grow < NN && kp < KK)
                    f2 = *(const float2*)&A[(size_t)grow * KK + kp];
                v[2 * j]     = f2b(f2.x);
                v[2 * j + 1] = f2b(f2.y);
            }
            *(bf16x8*)&As[rr * LDK + kch] = *(bf16x8*)v;
        }
        // stage B: 128 cols x 32 k from padded bf16 Bt[n][k]
        #pragma unroll
        for (int i = 0; i < 2; ++i) {
            int c   = i * 256 + t;
            int nn  = c >> 2;
            int kch = (c & 3) * 8;
            bf16x8 vv = *(const bf16x8*)&Bt[(size_t)(col0 + nn) * KP + kc + kch];
            *(bf16x8*)&Bs[nn * LDK + kch] = vv;
        }
        __syncthreads();

        bf16x8 a[4], b[4];
        #pragma unroll
        for (int mi = 0; mi < 4; ++mi)
            a[mi] = *(const bf16x8*)&As[(wm + mi * 16 + r16) * LDK + q * 8];
        #pragma unroll
        for (int ni = 0; ni < 4; ++ni)
            b[ni] = *(const bf16x8*)&Bs[(wn + ni * 16 + r16) * LDK + q * 8];
        #pragma unroll
        for (int mi = 0; mi < 4; ++mi)
            #pragma unroll
            for (int ni = 0; ni < 4; ++ni)
                acc[mi][ni] = __builtin_amdgcn_mfma_f32_16x16x32_bf16(a[mi], b[ni], acc[mi][ni], 0, 0, 0);
        __syncthreads();
    }

    // epilogue: bias + bf16 store. D layout: col=lane&15, row=q*4+reg
    #pragma unroll
    for (int ni = 0; ni < 4; ++ni) {
        int col = col0 + wn + ni * 16 + r16;
        float bb = (col < DE) ? bias[col] : 0.0f;
        #pragma unroll
        for (int mi = 0; mi < 4; ++mi) {
            #pragma unroll
            for (int ri = 0; ri < 4; ++ri) {
                int row = row0 + wm + mi * 16 + q * 4 + ri;
                if (row < NN && col < DE) {
                    C[(size_t)row * DE + col] = __float2bfloat16(acc[mi][ni][ri] + bb);
                }
            }
        }
    }
}

// ---------------- one wave per edge: out[tgt] += prop[src,e,:] * gating[pos,:]
__global__ __launch_bounds__(256) void edge_kernel(const int* __restrict__ edges,
                                                   const int* __restrict__ pos_lists,
                                                   const __hip_bfloat16* __restrict__ prop,
                                                   const float* __restrict__ gating,
                                                   float* __restrict__ out,
                                                   float* __restrict__ bincount) {
    int wid = blockIdx.x * 4 + (threadIdx.x >> 6);
    if (wid >= ET * MM) return;
    int lane = threadIdx.x & 63;
    int e = wid / MM;
    int2 st = *(const int2*)&edges[2 * wid];
    int src = st.x, tgt = st.y;
    int pos = pos_lists[wid];
    const __hip_bfloat16* pr = prop + (size_t)src * DE + e * DD;
    const float* gr = gating + (size_t)pos * DD;
    float* orow = out + (size_t)tgt * DD;
    int d = lane * 4;
    if (d < DD) {
        __hip_bfloat162 p01 = *(const __hip_bfloat162*)&pr[d];
        float2 g01 = *(const float2*)&gr[d];
        atomicAdd(&orow[d + 0], __bfloat162float(p01.x) * g01.x);
        atomicAdd(&orow[d + 1], __bfloat162float(p01.y) * g01.y);
        if (d + 2 < DD) {
            __hip_bfloat162 p23 = *(const __hip_bfloat162*)&pr[d + 2];
            float2 g23 = *(const float2*)&gr[d + 2];
            atomicAdd(&orow[d + 2], __bfloat162float(p23.x) * g23.x);
            atomicAdd(&orow[d + 3], __bfloat162float(p23.y) * g23.y);
        }
    }
    if (lane == 0) atomicAdd(&bincount[tgt], 1.0f);
}

// ---------------- out /= (bincount==0 ? 1 : bincount) + 1e-8, float2
__global__ void divide_kernel(float2* __restrict__ out, const float* __restrict__ bincount) {
    size_t i = (size_t)blockIdx.x * blockDim.x + threadIdx.x;
    if (i >= (size_t)NN * DD / 2) return;
    int n = (int)((2 * i) / DD);
    float c = bincount[n];
    float div = (c == 0.0f ? 1.0f : c) + 1e-8f;
    float2 v = out[i];
    v.x /= div; v.y /= div;
    out[i] = v;
}

extern "C" void kernel_launch(void* const* d_in, const int* in_sizes, int n_in,
                              void* d_out, int out_size, void* d_ws, size_t ws_size,
                              hipStream_t stream) {
    const float* node_states = (const float*)d_in[0];
    const int*   edges       = (const int*)d_in[1];
    const int*   pos_lists   = (const int*)d_in[2];
    const float* W_transform = (const float*)d_in[3];
    const float* b_transform = (const float*)d_in[4];
    const float* W_pos       = (const float*)d_in[5];
    const float* b_pos       = (const float*)d_in[6];
    float* out = (float*)d_out;

    // workspace layout (all 16B-aligned)
    float* gating   = (float*)d_ws;                          // 512*202*4   = 413,696 B
    float* bincount = gating + NPOS * DD;                    // 100000*4    = 400,000 B
    __hip_bfloat16* Bt = (__hip_bfloat16*)(bincount + NN);   // 1280*224*2  = 573,440 B
    __hip_bfloat16* prop = Bt + NP * KP;                     // 100000*1212*2 = 242,400,000 B

    hipMemsetAsync(d_out, 0, (size_t)NN * DD * sizeof(float), stream);
    hipMemsetAsync(bincount, 0, NN * sizeof(float), stream);

    gating_kernel<<<NPOS, 256, 0, stream>>>(W_pos, b_pos, gating);
    convB_kernel<<<(NP * KP + 255) / 256, 256, 0, stream>>>(W_transform, Bt);

    dim3 g2((DE + 127) / 128, (NN + 127) / 128);
    gemm_mfma<<<g2, 256, 0, stream>>>(node_states, Bt, b_transform, prop);

    edge_kernel<<<(ET * MM) / 4, 256, 0, stream>>>(edges, pos_lists, prop, gating, out, bincount);

    divide_kernel<<<(int)(((size_t)NN * DD / 2 + 255) / 256), 256, 0, stream>>>((float2*)out, bincount);
}

// Round 3
// 1104.578 us; speedup vs baseline: 3.6810x; 3.6810x over previous
//
#include <hip/hip_runtime.h>
#include <hip/hip_bf16.h>
#include <math.h>

#define NN   100000   // nodes
#define DD   202      // feature dim
#define ET   6        // edge types
#define MM   200000   // edges per type
#define NE   (ET*MM)  // 1.2M edges
#define NPOS 512
#define DE   1212     // DD*ET
#define KK   202      // GEMM K
#define KP   224      // K padded to 7*32
#define NP   1280     // N padded to 10*128
#define LDK  40       // LDS k-stride (32 + 8 pad)

typedef __attribute__((ext_vector_type(8))) short bf16x8;
typedef __attribute__((ext_vector_type(4))) float f32x4;

static __device__ inline short f2b(float f) {
    __hip_bfloat16 h = __float2bfloat16(f);
    union { __hip_bfloat16 h; short s; } u; u.h = h; return u.s;
}

// ---------------- pos_gating: (512 x 202) = 2*sigmoid(pos_embs @ W_pos + b_pos)
__global__ void gating_kernel(const float* __restrict__ W_pos,
                              const float* __restrict__ b_pos,
                              float* __restrict__ gating) {
    int p = blockIdx.x;
    __shared__ float emb[DD];
    int t = threadIdx.x;
    if (t < 100) {
        float invf = expf(-((float)t / 100.0f) * 9.210340371976184f); // ln(10000)
        float si = (float)p * invf;
        emb[t]       = sinf(si);
        emb[100 + t] = cosf(si);
    } else if (t < 102) {
        emb[100 + t] = 0.0f;
    }
    __syncthreads();
    if (t < DD) {
        float acc = b_pos[t];
        for (int k = 0; k < DD; ++k) acc += emb[k] * W_pos[k * DD + t];
        gating[p * DD + t] = 2.0f / (1.0f + expf(-acc));
    }
}

// ---------------- W_transform (202x1212 fp32) -> Bt (1280x224 bf16, transposed, padded)
__global__ void convB_kernel(const float* __restrict__ W, __hip_bfloat16* __restrict__ Bt) {
    int id = blockIdx.x * 256 + threadIdx.x;
    if (id >= NP * KP) return;
    int n = id / KP, k = id % KP;
    float v = (k < KK && n < DE) ? W[(size_t)k * DE + n] : 0.0f;
    Bt[id] = __float2bfloat16(v);
}

// ---------------- prop = A(100000x202 fp32) @ W + b -> bf16, MFMA 128x128 tile
__global__ __launch_bounds__(256) void gemm_mfma(const float* __restrict__ A,
                                                 const __hip_bfloat16* __restrict__ Bt,
                                                 const float* __restrict__ bias,
                                                 __hip_bfloat16* __restrict__ C) {
    __shared__ short As[128 * LDK];
    __shared__ short Bs[128 * LDK];
    int t    = threadIdx.x;
    int lane = t & 63;
    int wave = t >> 6;
    int wm   = (wave >> 1) * 64;
    int wn   = (wave & 1) * 64;
    int q    = lane >> 4;
    int r16  = lane & 15;
    int row0 = blockIdx.y * 128;
    int col0 = blockIdx.x * 128;

    f32x4 acc[4][4] = {};

    for (int kc = 0; kc < KP; kc += 32) {
        #pragma unroll
        for (int i = 0; i < 2; ++i) {
            int c   = i * 256 + t;
            int rr  = c >> 2;
            int kch = (c & 3) * 8;
            int grow = row0 + rr;
            short v[8];
            #pragma unroll
            for (int j = 0; j < 4; ++j) {
                int kp = kc + kch + 2 * j;
                float2 f2 = make_float2(0.0f, 0.0f);
                if (grow < NN && kp < KK)
                    f2 = *(const float2*)&A[(size_t)grow * KK + kp];
                v[2 * j]     = f2b(f2.x);
                v[2 * j + 1] = f2b(f2.y);
            }
            *(bf16x8*)&As[rr * LDK + kch] = *(bf16x8*)v;
        }
        #pragma unroll
        for (int i = 0; i < 2; ++i) {
            int c   = i * 256 + t;
            int nn  = c >> 2;
            int kch = (c & 3) * 8;
            bf16x8 vv = *(const bf16x8*)&Bt[(size_t)(col0 + nn) * KP + kc + kch];
            *(bf16x8*)&Bs[nn * LDK + kch] = vv;
        }
        __syncthreads();

        bf16x8 a[4], b[4];
        #pragma unroll
        for (int mi = 0; mi < 4; ++mi)
            a[mi] = *(const bf16x8*)&As[(wm + mi * 16 + r16) * LDK + q * 8];
        #pragma unroll
        for (int ni = 0; ni < 4; ++ni)
            b[ni] = *(const bf16x8*)&Bs[(wn + ni * 16 + r16) * LDK + q * 8];
        #pragma unroll
        for (int mi = 0; mi < 4; ++mi)
            #pragma unroll
            for (int ni = 0; ni < 4; ++ni)
                acc[mi][ni] = __builtin_amdgcn_mfma_f32_16x16x32_bf16(a[mi], b[ni], acc[mi][ni], 0, 0, 0);
        __syncthreads();
    }

    #pragma unroll
    for (int ni = 0; ni < 4; ++ni) {
        int col = col0 + wn + ni * 16 + r16;
        float bb = (col < DE) ? bias[col] : 0.0f;
        #pragma unroll
        for (int mi = 0; mi < 4; ++mi) {
            #pragma unroll
            for (int ri = 0; ri < 4; ++ri) {
                int row = row0 + wm + mi * 16 + q * 4 + ri;
                if (row < NN && col < DE) {
                    C[(size_t)row * DE + col] = __float2bfloat16(acc[mi][ni][ri] + bb);
                }
            }
        }
    }
}

// ---------------- pass 1: histogram of targets
__global__ __launch_bounds__(256) void count_kernel(const int* __restrict__ edges,
                                                    int* __restrict__ count) {
    int i = blockIdx.x * 256 + threadIdx.x;
    if (i >= NE) return;
    atomicAdd(&count[edges[2 * i + 1]], 1);
}

// ---------------- pass 2: segment allocation (block scan + 1 atomic/block)
__global__ __launch_bounds__(256) void alloc_kernel(const int* __restrict__ count,
                                                    int* __restrict__ start,
                                                    int* __restrict__ cursor) {
    int t = blockIdx.x * 256 + threadIdx.x;
    int c = (t < NN) ? count[t] : 0;
    __shared__ int s[256];
    __shared__ int base;
    s[threadIdx.x] = c;
    __syncthreads();
    int v = c;
    for (int off = 1; off < 256; off <<= 1) {
        int u = (threadIdx.x >= off) ? s[threadIdx.x - off] : 0;
        __syncthreads();
        v += u;
        s[threadIdx.x] = v;
        __syncthreads();
    }
    if (threadIdx.x == 255) base = atomicAdd(cursor, v);
    __syncthreads();
    if (t < NN) start[t] = base + v - c;   // exclusive offset
}

// ---------------- pass 3: scatter edge ids into segments (start becomes segment END)
__global__ __launch_bounds__(256) void scatter_kernel(const int* __restrict__ edges,
                                                      int* __restrict__ start,
                                                      int* __restrict__ eidx) {
    int i = blockIdx.x * 256 + threadIdx.x;
    if (i >= NE) return;
    int tgt = edges[2 * i + 1];
    int p = atomicAdd(&start[tgt], 1);
    eidx[p] = i;
}

// ---------------- pass 4: one wave per target — gather, gate, mean, store (no atomics)
__global__ __launch_bounds__(256) void gather_kernel(const int* __restrict__ edges,
                                                     const int* __restrict__ pos_lists,
                                                     const __hip_bfloat16* __restrict__ prop,
                                                     const float* __restrict__ gating,
                                                     const int* __restrict__ count,
                                                     const int* __restrict__ seg_end,
                                                     const int* __restrict__ eidx,
                                                     float* __restrict__ out) {
    int wid = blockIdx.x * 4 + (threadIdx.x >> 6);
    if (wid >= NN) return;
    int lane = threadIdx.x & 63;
    int c = count[wid];
    int end = seg_end[wid];
    int begin = end - c;
    int d = lane * 4;
    float a0 = 0.f, a1 = 0.f, a2 = 0.f, a3 = 0.f;
    for (int j = begin; j < end; ++j) {
        int idx = eidx[j];
        int e = idx / MM;
        int src = edges[2 * idx];
        int pos = pos_lists[idx];
        const __hip_bfloat16* pr = prop + (size_t)src * DE + e * DD;
        const float* gr = gating + (size_t)pos * DD;
        if (d < DD) {
            __hip_bfloat162 p01 = *(const __hip_bfloat162*)&pr[d];
            float2 g01 = *(const float2*)&gr[d];
            a0 += __bfloat162float(p01.x) * g01.x;
            a1 += __bfloat162float(p01.y) * g01.y;
            if (d + 2 < DD) {
                __hip_bfloat162 p23 = *(const __hip_bfloat162*)&pr[d + 2];
                float2 g23 = *(const float2*)&gr[d + 2];
                a2 += __bfloat162float(p23.x) * g23.x;
                a3 += __bfloat162float(p23.y) * g23.y;
            }
        }
    }
    float div = (c == 0 ? 1.0f : (float)c) + 1e-8f;
    float inv = 1.0f / div;
    float* orow = out + (size_t)wid * DD;
    if (d < DD) {
        *(float2*)&orow[d] = make_float2(a0 * inv, a1 * inv);
        if (d + 2 < DD)
            *(float2*)&orow[d + 2] = make_float2(a2 * inv, a3 * inv);
    }
}

extern "C" void kernel_launch(void* const* d_in, const int* in_sizes, int n_in,
                              void* d_out, int out_size, void* d_ws, size_t ws_size,
                              hipStream_t stream) {
    const float* node_states = (const float*)d_in[0];
    const int*   edges       = (const int*)d_in[1];
    const int*   pos_lists   = (const int*)d_in[2];
    const float* W_transform = (const float*)d_in[3];
    const float* b_transform = (const float*)d_in[4];
    const float* W_pos       = (const float*)d_in[5];
    const float* b_pos       = (const float*)d_in[6];
    float* out = (float*)d_out;

    // workspace layout (all 16B-aligned)
    float* gating   = (float*)d_ws;                          // 413,696 B
    int*   count    = (int*)(gating + NPOS * DD);            // 400,000 B
    int*   start    = count + NN;                            // 400,000 B
    int*   cursor   = start + NN;                            // 16 B
    __hip_bfloat16* Bt = (__hip_bfloat16*)(cursor + 4);      // 573,440 B
    int*   eidx     = (int*)(Bt + NP * KP);                  // 4,800,000 B
    __hip_bfloat16* prop = (__hip_bfloat16*)(eidx + NE);     // 242,400,000 B

    hipMemsetAsync(count, 0, NN * sizeof(int), stream);
    hipMemsetAsync(cursor, 0, sizeof(int), stream);

    gating_kernel<<<NPOS, 256, 0, stream>>>(W_pos, b_pos, gating);
    convB_kernel<<<(NP * KP + 255) / 256, 256, 0, stream>>>(W_transform, Bt);

    dim3 g2((DE + 127) / 128, (NN + 127) / 128);
    gemm_mfma<<<g2, 256, 0, stream>>>(node_states, Bt, b_transform, prop);

    count_kernel<<<(NE + 255) / 256, 256, 0, stream>>>(edges, count);
    alloc_kernel<<<(NN + 255) / 256, 256, 0, stream>>>(count, start, cursor);
    scatter_kernel<<<(NE + 255) / 256, 256, 0, stream>>>(edges, start, eidx);
    gather_kernel<<<(NN + 3) / 4, 256, 0, stream>>>(edges, pos_lists, prop, gating,
                                                    count, start, eidx, out);
}

// Round 4
// 670.676 us; speedup vs baseline: 6.0624x; 1.6470x over previous
//
#include <hip/hip_runtime.h>
#include <hip/hip_bf16.h>
#include <math.h>

#define NN   100000   // nodes
#define NNP  100096   // nodes padded to mult of 128 (GEMM staging reads, zero-filled)
#define DD   202      // feature dim
#define ET   6        // edge types
#define MM   200000   // edges per type
#define NE   (ET*MM)  // 1.2M edges
#define NPOS 512
#define GDP  204      // gating row stride (padded, zeros at 202..203)
#define DE   1212     // DD*ET
#define PDE  1216     // prop row stride (padded; 2432 B rows -> 16B-aligned, 64B-aligned)
#define KK   202      // GEMM K
#define KP   224      // K padded to 7*32
#define NP   1280     // N padded to 10*128

typedef __attribute__((ext_vector_type(8))) short bf16x8;
typedef __attribute__((ext_vector_type(4))) float f32x4;

static __device__ inline unsigned short f2b(float f) {
    union { __hip_bfloat16 h; unsigned short s; } u;
    u.h = __float2bfloat16(f);
    return u.s;
}

static __device__ inline void glds16(const unsigned short* g, unsigned short* l) {
    __builtin_amdgcn_global_load_lds(
        (const __attribute__((address_space(1))) unsigned int*)g,
        (__attribute__((address_space(3))) unsigned int*)l, 16, 0, 0);
}

// ---------------- pos_gating: (512 x GDP) = 2*sigmoid(pos_embs @ W_pos + b_pos), padded
__global__ void gating_kernel(const float* __restrict__ W_pos,
                              const float* __restrict__ b_pos,
                              float* __restrict__ gating) {
    int p = blockIdx.x;
    __shared__ float emb[DD];
    int t = threadIdx.x;
    if (t < 100) {
        float invf = expf(-((float)t / 100.0f) * 9.210340371976184f); // ln(10000)
        float si = (float)p * invf;
        emb[t]       = sinf(si);
        emb[100 + t] = cosf(si);
    } else if (t < 102) {
        emb[100 + t] = 0.0f;
    }
    __syncthreads();
    if (t < GDP) {
        float g = 0.0f;
        if (t < DD) {
            float acc = b_pos[t];
            for (int k = 0; k < DD; ++k) acc += emb[k] * W_pos[k * DD + t];
            g = 2.0f / (1.0f + expf(-acc));
        }
        gating[p * GDP + t] = g;   // zeros at 202,203
    }
}

// ---------------- W_transform (202x1212 fp32) -> Bt (1280x224 bf16, transposed, padded)
__global__ void convB_kernel(const float* __restrict__ W, unsigned short* __restrict__ Bt) {
    int id = blockIdx.x * 256 + threadIdx.x;
    if (id >= NP * KP) return;
    int n = id / KP, k = id % KP;
    float v = (k < KK && n < DE) ? W[(size_t)k * DE + n] : 0.0f;
    Bt[id] = f2b(v);
}

// ---------------- node_states (100000x202 fp32) -> Abf (100096x224 bf16, padded)
__global__ void convA_kernel(const float* __restrict__ A, unsigned short* __restrict__ Abf) {
    int id = blockIdx.x * 256 + threadIdx.x;         // one bf16 pair per thread
    if (id >= NNP * (KP / 2)) return;
    int row = id / (KP / 2), kp = (id % (KP / 2)) * 2;
    float2 v = make_float2(0.0f, 0.0f);
    if (row < NN && kp < KK) v = *(const float2*)&A[(size_t)row * KK + kp]; // kp<=200 -> ok
    ushort2 o; o.x = f2b(v.x); o.y = f2b(v.y);
    *(ushort2*)&Abf[(size_t)row * KP + kp] = o;
}

// ---------------- prop = Abf @ Bt^T + b -> bf16[NN][PDE], MFMA 128x128 tile
// global_load_lds staging (16B), XOR-swizzled LDS chunks, LDS-staged epilogue
__global__ __launch_bounds__(256) void gemm_mfma(const unsigned short* __restrict__ Abf,
                                                 const unsigned short* __restrict__ Bt,
                                                 const float* __restrict__ bias,
                                                 unsigned short* __restrict__ C) {
    __shared__ unsigned short sA[4096];   // 128 rows x 32 k (swizzled chunks)
    __shared__ unsigned short sB[4096];
    __shared__ unsigned short sE[4608];   // epilogue: 4 waves x 16 rows x 72 (stride-padded)
    int t    = threadIdx.x;
    int lane = t & 63;
    int wave = t >> 6;
    int q    = lane >> 4;
    int r16  = lane & 15;
    int wm   = (wave >> 1) * 64;
    int wn   = (wave & 1) * 64;
    int row0 = blockIdx.y * 128;
    int col0 = blockIdx.x * 128;

    // staging geometry: lane covers 16B; rows wave*32+i*16+lrow; chunk XOR-swizzled
    int lrow = lane >> 2;
    int gch  = (lane & 3) ^ ((lrow >> 1) & 3);     // global k-chunk this lane fetches
    const unsigned short* aS0 = Abf + (size_t)(row0 + wave * 32 + lrow) * KP + gch * 8;
    const unsigned short* aS1 = aS0 + 16 * KP;
    const unsigned short* bS0 = Bt  + (size_t)(col0 + wave * 32 + lrow) * KP + gch * 8;
    const unsigned short* bS1 = bS0 + 16 * KP;
    unsigned short* lA0 = &sA[(wave * 32) * 32];
    unsigned short* lA1 = &sA[(wave * 32 + 16) * 32];
    unsigned short* lB0 = &sB[(wave * 32) * 32];
    unsigned short* lB1 = &sB[(wave * 32 + 16) * 32];

    f32x4 acc[4][4] = {};
    int swzr = (r16 >> 1) & 3;

    for (int kc = 0; kc < KP; kc += 32) {
        glds16(aS0 + kc, lA0);
        glds16(aS1 + kc, lA1);
        glds16(bS0 + kc, lB0);
        glds16(bS1 + kc, lB1);
        __syncthreads();

        bf16x8 a[4], b[4];
        #pragma unroll
        for (int mi = 0; mi < 4; ++mi)
            a[mi] = *(const bf16x8*)&sA[(wm + mi * 16 + r16) * 32 + (q ^ swzr) * 8];
        #pragma unroll
        for (int ni = 0; ni < 4; ++ni)
            b[ni] = *(const bf16x8*)&sB[(wn + ni * 16 + r16) * 32 + (q ^ swzr) * 8];
        #pragma unroll
        for (int mi = 0; mi < 4; ++mi)
            #pragma unroll
            for (int ni = 0; ni < 4; ++ni)
                acc[mi][ni] = __builtin_amdgcn_mfma_f32_16x16x32_bf16(a[mi], b[ni], acc[mi][ni], 0, 0, 0);
        __syncthreads();
    }

    // epilogue: per-wave-private LDS staging -> 16B/lane aligned stores
    float bb[4];
    #pragma unroll
    for (int ni = 0; ni < 4; ++ni) {
        int col = col0 + wn + ni * 16 + r16;
        bb[ni] = (col < DE) ? bias[col] : 0.0f;
    }
    int epi = wave * 1152;            // 16 rows * 72
    int rl = lane >> 3, ck = lane & 7;
    #pragma unroll
    for (int mi = 0; mi < 4; ++mi) {
        #pragma unroll
        for (int ni = 0; ni < 4; ++ni)
            #pragma unroll
            for (int ri = 0; ri < 4; ++ri)
                sE[epi + (q * 4 + ri) * 72 + ni * 16 + r16] = f2b(acc[mi][ni][ri] + bb[ni]);
        #pragma unroll
        for (int ii = 0; ii < 2; ++ii) {
            int rr = ii * 8 + rl;
            bf16x8 v = *(const bf16x8*)&sE[epi + rr * 72 + ck * 8];
            int grow = row0 + wm + mi * 16 + rr;
            int gcol = col0 + wn + ck * 8;
            if (grow < NN && gcol < PDE)
                *(bf16x8*)&C[(size_t)grow * PDE + gcol] = v;
        }
    }
}

// ---------------- pass 1: histogram of targets
__global__ __launch_bounds__(256) void count_kernel(const int* __restrict__ edges,
                                                    int* __restrict__ count) {
    int i = blockIdx.x * 256 + threadIdx.x;
    if (i >= NE) return;
    atomicAdd(&count[edges[2 * i + 1]], 1);
}

// ---------------- pass 2: segment allocation (block scan + 1 atomic/block)
__global__ __launch_bounds__(256) void alloc_kernel(const int* __restrict__ count,
                                                    int* __restrict__ start,
                                                    int* __restrict__ cursor) {
    int t = blockIdx.x * 256 + threadIdx.x;
    int c = (t < NN) ? count[t] : 0;
    __shared__ int s[256];
    __shared__ int base;
    s[threadIdx.x] = c;
    __syncthreads();
    int v = c;
    for (int off = 1; off < 256; off <<= 1) {
        int u = (threadIdx.x >= off) ? s[threadIdx.x - off] : 0;
        __syncthreads();
        v += u;
        s[threadIdx.x] = v;
        __syncthreads();
    }
    if (threadIdx.x == 255) base = atomicAdd(cursor, v);
    __syncthreads();
    if (t < NN) start[t] = base + v - c;
}

// ---------------- pass 3: scatter edge ids (start becomes segment END)
__global__ __launch_bounds__(256) void scatter_kernel(const int* __restrict__ edges,
                                                      int* __restrict__ start,
                                                      int* __restrict__ eidx) {
    int i = blockIdx.x * 256 + threadIdx.x;
    if (i >= NE) return;
    int tgt = edges[2 * i + 1];
    int p = atomicAdd(&start[tgt], 1);
    eidx[p] = i;
}

// ---------------- pass 4: one wave per target; shfl-broadcast metadata; pipelined gathers
__global__ __launch_bounds__(256) void gather_kernel(const int* __restrict__ edges,
                                                     const int* __restrict__ pos_lists,
                                                     const unsigned short* __restrict__ prop,
                                                     const float* __restrict__ gating,
                                                     const int* __restrict__ count,
                                                     const int* __restrict__ seg_end,
                                                     const int* __restrict__ eidx,
                                                     float* __restrict__ out) {
    int wid = blockIdx.x * 4 + (threadIdx.x >> 6);
    if (wid >= NN) return;
    int lane = threadIdx.x & 63;
    int c = count[wid];
    int end = seg_end[wid];
    int begin = end - c;
    int d = lane * 4;
    bool act = d < DD;                    // lanes 0..50
    float a0 = 0.f, a1 = 0.f, a2 = 0.f, a3 = 0.f;

    for (int base = begin; base < end; base += 64) {
        int n = end - base; if (n > 64) n = 64;
        int idx = 0;
        if (lane < n) idx = eidx[base + lane];
        int src = edges[2 * idx];
        int pos = pos_lists[idx];
        int e   = (int)((unsigned)idx / MM);
        int poff = src * PDE + e * DD;    // < 2^27, fits int
        int goff = pos * GDP;

        int po = __shfl(poff, 0), go = __shfl(goff, 0);
        uint2  pv = make_uint2(0u, 0u);
        float4 gv = make_float4(0.f, 0.f, 0.f, 0.f);
        if (act && n > 0) {
            pv = *(const uint2*)&prop[po + d];
            gv = *(const float4*)&gating[go + d];
        }
        for (int jj = 0; jj < n; ++jj) {
            int nx = (jj + 1 < n) ? jj + 1 : jj;
            int po2 = __shfl(poff, nx);
            int go2 = __shfl(goff, nx);
            uint2  pv2 = pv;
            float4 gv2 = gv;
            if (act && jj + 1 < n) {
                pv2 = *(const uint2*)&prop[po2 + d];
                gv2 = *(const float4*)&gating[go2 + d];
            }
            float p0 = __uint_as_float(pv.x << 16);
            float p1 = __uint_as_float(pv.x & 0xffff0000u);
            float p2 = __uint_as_float(pv.y << 16);
            float p3 = __uint_as_float(pv.y & 0xffff0000u);
            a0 += p0 * gv.x; a1 += p1 * gv.y; a2 += p2 * gv.z; a3 += p3 * gv.w;
            pv = pv2; gv = gv2;
        }
    }

    float div = (c == 0 ? 1.0f : (float)c) + 1e-8f;
    float inv = 1.0f / div;
    if (act) {
        float* orow = out + (size_t)wid * DD;
        *(float2*)&orow[d] = make_float2(a0 * inv, a1 * inv);
        if (d + 2 < DD) *(float2*)&orow[d + 2] = make_float2(a2 * inv, a3 * inv);
    }
}

extern "C" void kernel_launch(void* const* d_in, const int* in_sizes, int n_in,
                              void* d_out, int out_size, void* d_ws, size_t ws_size,
                              hipStream_t stream) {
    const float* node_states = (const float*)d_in[0];
    const int*   edges       = (const int*)d_in[1];
    const int*   pos_lists   = (const int*)d_in[2];
    const float* W_transform = (const float*)d_in[3];
    const float* b_transform = (const float*)d_in[4];
    const float* W_pos       = (const float*)d_in[5];
    const float* b_pos       = (const float*)d_in[6];
    float* out = (float*)d_out;

    // workspace layout (16B-aligned blocks)
    float* gating   = (float*)d_ws;                               // 512*204*4    = 417,792 B
    int*   count    = (int*)(gating + NPOS * GDP);                // 400,000 B
    int*   start    = count + NN;                                 // 400,000 B
    int*   cursor   = start + NN;                                 // 16 B
    unsigned short* Bt  = (unsigned short*)(cursor + 4);          // 1280*224*2   = 573,440 B
    unsigned short* Abf = Bt + NP * KP;                           // 100096*224*2 = 44,843,008 B
    int*   eidx     = (int*)(Abf + (size_t)NNP * KP);             // 4,800,000 B
    unsigned short* prop = (unsigned short*)(eidx + NE);          // 100000*1216*2 = 243,200,000 B

    hipMemsetAsync(count, 0, NN * sizeof(int), stream);
    hipMemsetAsync(cursor, 0, sizeof(int), stream);

    gating_kernel<<<NPOS, 256, 0, stream>>>(W_pos, b_pos, gating);
    convB_kernel<<<(NP * KP + 255) / 256, 256, 0, stream>>>(W_transform, Bt);
    convA_kernel<<<(NNP * (KP / 2) + 255) / 256, 256, 0, stream>>>(node_states, Abf);

    dim3 g2(NP / 128, NNP / 128);
    gemm_mfma<<<g2, 256, 0, stream>>>(Abf, Bt, b_transform, prop);

    count_kernel<<<(NE + 255) / 256, 256, 0, stream>>>(edges, count);
    alloc_kernel<<<(NN + 255) / 256, 256, 0, stream>>>(count, start, cursor);
    scatter_kernel<<<(NE + 255) / 256, 256, 0, stream>>>(edges, start, eidx);
    gather_kernel<<<(NN + 3) / 4, 256, 0, stream>>>(edges, pos_lists, prop, gating,
                                                    count, start, eidx, out);
}